// Round 2
// baseline (1909.008 us; speedup 1.0000x reference)
//
#include <hip/hip_runtime.h>
#include <hip/hip_bf16.h>

// ---------------- constants ----------------
#define SEQ      2048
#define BATCH    2
#define DMODEL   1024
#define NHEADS   16
#define HDIM     64
#define FFN_DIM  4096
#define MROWS    (BATCH*SEQ)   // 4096

typedef __attribute__((ext_vector_type(8))) short bf16x8;
typedef __attribute__((ext_vector_type(4))) float f32x4;

// ---------------- helpers ----------------
__device__ __forceinline__ unsigned short f2b(float f) {
    union { float f; unsigned int u; } v; v.f = f;
    unsigned int u = v.u;
    return (unsigned short)((u + 0x7FFFu + ((u >> 16) & 1u)) >> 16);  // RNE
}
__device__ __forceinline__ float b2f(unsigned short h) {
    union { unsigned int u; float f; } v; v.u = ((unsigned int)h) << 16;
    return v.f;
}
__device__ __forceinline__ void gload_lds16(const void* g, void* l) {
    __builtin_amdgcn_global_load_lds((const __attribute__((address_space(1))) void*)g,
                                     (__attribute__((address_space(3))) void*)l, 16, 0, 0);
}

// ---------------- W [K][N] f32 -> Wt [N][K] bf16 ----------------
__global__ __launch_bounds__(256) void wtrans(const float* __restrict__ W,
                                              unsigned short* __restrict__ Wt,
                                              int K, int N) {
    __shared__ float t[32][33];
    const int n0 = blockIdx.x * 32, k0 = blockIdx.y * 32;
    const int tx = threadIdx.x, ty = threadIdx.y;   // 32 x 8
#pragma unroll
    for (int i = 0; i < 4; i++)
        t[ty + i * 8][tx] = W[(size_t)(k0 + ty + i * 8) * N + n0 + tx];
    __syncthreads();
#pragma unroll
    for (int i = 0; i < 4; i++) {
        const int n = ty + i * 8;
        Wt[(size_t)(n0 + n) * K + k0 + tx] = f2b(t[tx][n]);
    }
}

// ---------------- f32 -> bf16 flat ----------------
__global__ __launch_bounds__(256) void tobf16(const float* __restrict__ in,
                                              unsigned short* __restrict__ out, int n) {
    const int i = (blockIdx.x * 256 + threadIdx.x) * 8;
    if (i >= n) return;
    float4 a = *(const float4*)(in + i);
    float4 b = *(const float4*)(in + i + 4);
    unsigned short r[8] = {f2b(a.x), f2b(a.y), f2b(a.z), f2b(a.w),
                           f2b(b.x), f2b(b.y), f2b(b.z), f2b(b.w)};
    *(uint4*)(out + i) = *(const uint4*)r;
}

// ---------------- bf16 MFMA GEMM: C[M,N] = A[M,K] @ Bt[N,K]^T + bias ----------------
// m97 structure: 128x128 tile, BK=32, 4 waves (2x2 of 64x64), global_load_lds w=16.
template <int RELU, int WF32, int WB16>
__global__ __launch_bounds__(256) void gemm_bt(const unsigned short* __restrict__ A,
                                               const unsigned short* __restrict__ Bt,
                                               const float* __restrict__ bias,
                                               float* __restrict__ Cf,
                                               unsigned short* __restrict__ Cb,
                                               int M, int N, int K) {
    __shared__ __align__(16) unsigned short As[128 * 32];
    __shared__ __align__(16) unsigned short Bs[128 * 32];
    const int tid  = threadIdx.x;
    const int lane = tid & 63;
    const int w    = tid >> 6;
    const int m0   = blockIdx.y << 7;
    const int n0   = blockIdx.x << 7;
    const int wr   = (w >> 1) << 6;
    const int wc   = (w & 1) << 6;
    const int srow = lane >> 2;          // staging: row within 16-row group
    const int scol = (lane & 3) << 3;    // staging: k offset (8 bf16 = 16B)

    f32x4 acc[4][4];
#pragma unroll
    for (int mi = 0; mi < 4; mi++)
#pragma unroll
        for (int ni = 0; ni < 4; ni++) acc[mi][ni] = (f32x4){0.f, 0.f, 0.f, 0.f};

    for (int k0 = 0; k0 < K; k0 += 32) {
#pragma unroll
        for (int t = 0; t < 2; t++) {
            const int rg  = w * 2 + t;                 // 16-row group 0..7
            const int row = (rg << 4) + srow;
            gload_lds16(A  + (size_t)(m0 + row) * K + k0 + scol, (char*)As + (rg << 10));
            gload_lds16(Bt + (size_t)(n0 + row) * K + k0 + scol, (char*)Bs + (rg << 10));
        }
        __syncthreads();
        const int fr = lane & 15;
        const int fk = (lane >> 4) << 3;
        bf16x8 af[4], bfr[4];
#pragma unroll
        for (int i = 0; i < 4; i++) {
            af[i]  = *(const bf16x8*)(As + (wr + (i << 4) + fr) * 32 + fk);
            bfr[i] = *(const bf16x8*)(Bs + (wc + (i << 4) + fr) * 32 + fk);
        }
#pragma unroll
        for (int mi = 0; mi < 4; mi++)
#pragma unroll
            for (int ni = 0; ni < 4; ni++)
                acc[mi][ni] = __builtin_amdgcn_mfma_f32_16x16x32_bf16(af[mi], bfr[ni], acc[mi][ni], 0, 0, 0);
        __syncthreads();
    }

    const int fr = lane & 15;
    const int fq = lane >> 4;
#pragma unroll
    for (int mi = 0; mi < 4; mi++) {
#pragma unroll
        for (int ni = 0; ni < 4; ni++) {
            const int col = n0 + wc + (ni << 4) + fr;
            const float bv = bias[col];
#pragma unroll
            for (int i = 0; i < 4; i++) {
                const int row = m0 + wr + (mi << 4) + (fq << 2) + i;
                float v = acc[mi][ni][i] + bv;
                if (RELU) v = fmaxf(v, 0.f);
                if (WF32) Cf[(size_t)row * N + col] = v;
                if (WB16) Cb[(size_t)row * N + col] = f2b(v);
            }
        }
    }
}

// ---------------- residual + LayerNorm (row = 1024) ----------------
template <int WB16>
__global__ __launch_bounds__(256) void resid_ln(const float* __restrict__ xin,
                                                const float* __restrict__ res,
                                                const float* __restrict__ g,
                                                const float* __restrict__ b,
                                                float* __restrict__ outf,
                                                unsigned short* __restrict__ outb) {
    const int row = blockIdx.x;
    const int tid = threadIdx.x;
    const size_t base = (size_t)row * 1024 + tid * 4;
    float4 xv = *(const float4*)(xin + base);
    float4 rv = *(const float4*)(res + base);
    const float v0 = xv.x + rv.x, v1 = xv.y + rv.y, v2 = xv.z + rv.z, v3 = xv.w + rv.w;
    float s  = v0 + v1 + v2 + v3;
    float sq = v0 * v0 + v1 * v1 + v2 * v2 + v3 * v3;
#pragma unroll
    for (int off = 32; off; off >>= 1) { s += __shfl_xor(s, off); sq += __shfl_xor(sq, off); }
    __shared__ float red[8];
    if ((tid & 63) == 0) { red[tid >> 6] = s; red[4 + (tid >> 6)] = sq; }
    __syncthreads();
    s  = red[0] + red[1] + red[2] + red[3];
    sq = red[4] + red[5] + red[6] + red[7];
    const float mean = s * (1.0f / 1024.0f);
    const float var  = sq * (1.0f / 1024.0f) - mean * mean;
    const float inv  = rsqrtf(var + 1e-5f);
    const int col = tid * 4;
    float4 gv = *(const float4*)(g + col);
    float4 bv = *(const float4*)(b + col);
    const float o0 = (v0 - mean) * inv * gv.x + bv.x;
    const float o1 = (v1 - mean) * inv * gv.y + bv.y;
    const float o2 = (v2 - mean) * inv * gv.z + bv.z;
    const float o3 = (v3 - mean) * inv * gv.w + bv.w;
    float4 ov = {o0, o1, o2, o3};
    *(float4*)(outf + base) = ov;
    if (WB16) {
        uint2 u;
        u.x = (unsigned int)f2b(o0) | ((unsigned int)f2b(o1) << 16);
        u.y = (unsigned int)f2b(o2) | ((unsigned int)f2b(o3) << 16);
        *(uint2*)(outb + base) = u;
    }
}

// ---------------- f32 flash attention (bf16 in/out), QBLK=KBLK=64 ----------------
// LDS rows of 64 floats, chunk-rotation swizzle kills stride-256B bank conflicts.
#define SWZ(r, cc) (((r) << 6) + ((((cc) + (r) + ((r) >> 2)) & 15) << 2))

__global__ __launch_bounds__(256) void attn_fwd(const unsigned short* __restrict__ Qb, int q_rs, int q_ho,
                                                const unsigned short* __restrict__ Kb, int k_rs, int k_ho,
                                                const unsigned short* __restrict__ Vb, int v_rs, int v_ho,
                                                const float* __restrict__ mask,
                                                unsigned short* __restrict__ Ob, int o_rs, int o_ho) {
    __shared__ __align__(16) float Qs[64 * 64];
    __shared__ __align__(16) float Ks[64 * 64];
    __shared__ __align__(16) float Vt[64 * 64];
    __shared__ __align__(16) float Ps[64 * 64];
    __shared__ float ms[64], fb[64], ls[64];
    __shared__ float redM[64 * 17], redS[64 * 17];

    const int tid = threadIdx.x;
    const int tq = tid >> 4, tk = tid & 15;
    const int bh = blockIdx.y;
    const int b = bh >> 4, h = bh & 15;
    const int q0 = blockIdx.x << 6;
    const size_t rowbase = (size_t)b * SEQ;

    // stage Q (pre-scaled by 1/sqrt(64) in f32 — exact pow2)
    for (int c = tid; c < 512; c += 256) {
        const int r = c >> 3, dc = (c & 7) << 3;
        uint4 raw = *(const uint4*)(Qb + (rowbase + q0 + r) * (size_t)q_rs + h * q_ho + dc);
        const unsigned short* u = (const unsigned short*)&raw;
#pragma unroll
        for (int j = 0; j < 8; j++) {
            const int col = dc + j;
            Qs[SWZ(r, col >> 2) + (col & 3)] = b2f(u[j]) * 0.125f;
        }
    }
    if (tid < 64) { ms[tid] = -3.0e38f; ls[tid] = 0.f; }

    float o[4][4] = {};

    for (int kv0 = 0; kv0 < SEQ; kv0 += 64) {
        __syncthreads();   // prev PV done; also covers Q stage / stat init on iter 0
        for (int c = tid; c < 512; c += 256) {
            const int r = c >> 3, dc = (c & 7) << 3;
            uint4 kraw = *(const uint4*)(Kb + (rowbase + kv0 + r) * (size_t)k_rs + h * k_ho + dc);
            uint4 vraw = *(const uint4*)(Vb + (rowbase + kv0 + r) * (size_t)v_rs + h * v_ho + dc);
            const unsigned short* ku = (const unsigned short*)&kraw;
            const unsigned short* vu = (const unsigned short*)&vraw;
#pragma unroll
            for (int j = 0; j < 8; j++) {
                const int col = dc + j;
                Ks[SWZ(r, col >> 2) + (col & 3)] = b2f(ku[j]);
                Vt[SWZ(col, r >> 2) + (r & 3)]   = b2f(vu[j]);   // transposed: Vt[d][kv]
            }
        }
        __syncthreads();

        // ---- QK^T (+mask) ----
        float sa[4][4];
#pragma unroll
        for (int i = 0; i < 4; i++) {
            float4 mk = *(const float4*)(mask + (size_t)(q0 + tq * 4 + i) * SEQ + kv0 + tk * 4);
            sa[i][0] = mk.x; sa[i][1] = mk.y; sa[i][2] = mk.z; sa[i][3] = mk.w;
        }
        for (int kk = 0; kk < 16; kk++) {
            float4 q4[4], k4[4];
#pragma unroll
            for (int i = 0; i < 4; i++) q4[i] = *(const float4*)&Qs[SWZ(tq * 4 + i, kk)];
#pragma unroll
            for (int j = 0; j < 4; j++) k4[j] = *(const float4*)&Ks[SWZ(tk * 4 + j, kk)];
#pragma unroll
            for (int i = 0; i < 4; i++)
#pragma unroll
                for (int j = 0; j < 4; j++) {
                    sa[i][j] = fmaf(q4[i].x, k4[j].x, sa[i][j]);
                    sa[i][j] = fmaf(q4[i].y, k4[j].y, sa[i][j]);
                    sa[i][j] = fmaf(q4[i].z, k4[j].z, sa[i][j]);
                    sa[i][j] = fmaf(q4[i].w, k4[j].w, sa[i][j]);
                }
        }
        // ---- online softmax ----
#pragma unroll
        for (int i = 0; i < 4; i++) {
            const float lm = fmaxf(fmaxf(sa[i][0], sa[i][1]), fmaxf(sa[i][2], sa[i][3]));
            redM[(tq * 4 + i) * 17 + tk] = lm;
        }
        __syncthreads();
        if (tid < 64) {
            float mt = redM[tid * 17];
#pragma unroll
            for (int t2 = 1; t2 < 16; t2++) mt = fmaxf(mt, redM[tid * 17 + t2]);
            const float mold = ms[tid];
            const float mnew = fmaxf(mold, mt);
            const float f = __expf(mold - mnew);
            ms[tid] = mnew; fb[tid] = f; ls[tid] *= f;
        }
        __syncthreads();
#pragma unroll
        for (int i = 0; i < 4; i++) {
            const int r = tq * 4 + i;
            const float mrow = ms[r], frow = fb[r];
            float ps = 0.f;
#pragma unroll
            for (int j = 0; j < 4; j++) {
                const float p = __expf(sa[i][j] - mrow);
                ps += p;
                Ps[SWZ(r, tk) + j] = p;
                o[i][j] *= frow;
            }
            redS[r * 17 + tk] = ps;
        }
        __syncthreads();
        if (tid < 64) {
            float ssum = 0.f;
#pragma unroll
            for (int t2 = 0; t2 < 16; t2++) ssum += redS[tid * 17 + t2];
            ls[tid] += ssum;
        }
        // ---- PV ----
        for (int kk = 0; kk < 16; kk++) {
            float4 p4[4], v4[4];
#pragma unroll
            for (int i = 0; i < 4; i++) p4[i] = *(const float4*)&Ps[SWZ(tq * 4 + i, kk)];
#pragma unroll
            for (int j = 0; j < 4; j++) v4[j] = *(const float4*)&Vt[SWZ(tk * 4 + j, kk)];
#pragma unroll
            for (int i = 0; i < 4; i++)
#pragma unroll
                for (int j = 0; j < 4; j++) {
                    o[i][j] = fmaf(p4[i].x, v4[j].x, o[i][j]);
                    o[i][j] = fmaf(p4[i].y, v4[j].y, o[i][j]);
                    o[i][j] = fmaf(p4[i].z, v4[j].z, o[i][j]);
                    o[i][j] = fmaf(p4[i].w, v4[j].w, o[i][j]);
                }
        }
    }
    __syncthreads();
#pragma unroll
    for (int i = 0; i < 4; i++) {
        const int r = tq * 4 + i;
        const float inv = 1.0f / ls[r];
        uint2 u;
        u.x = (unsigned int)f2b(o[i][0] * inv) | ((unsigned int)f2b(o[i][1] * inv) << 16);
        u.y = (unsigned int)f2b(o[i][2] * inv) | ((unsigned int)f2b(o[i][3] * inv) << 16);
        *(uint2*)(Ob + (rowbase + q0 + r) * (size_t)o_rs + h * o_ho + tk * 4) = u;
    }
}

// ---------------- orchestration ----------------
extern "C" void kernel_launch(void* const* d_in, const int* in_sizes, int n_in,
                              void* d_out, int out_size, void* d_ws, size_t ws_size,
                              hipStream_t stream) {
    const float* x     = (const float*)d_in[0];
    const float* y     = (const float*)d_in[1];
    const float* mask1 = (const float*)d_in[2];
    const float* mask2 = (const float*)d_in[3];
    const float* Wqkv  = (const float*)d_in[4];
    const float* bqkv  = (const float*)d_in[5];
    const float* Wo1   = (const float*)d_in[6];
    const float* bo1   = (const float*)d_in[7];
    const float* Wkv   = (const float*)d_in[8];
    const float* bkv   = (const float*)d_in[9];
    const float* Wq    = (const float*)d_in[10];
    const float* bq    = (const float*)d_in[11];
    const float* Wo2   = (const float*)d_in[12];
    const float* bo2   = (const float*)d_in[13];
    const float* g1    = (const float*)d_in[14];
    const float* b1    = (const float*)d_in[15];
    const float* g2    = (const float*)d_in[16];
    const float* b2    = (const float*)d_in[17];
    const float* g3    = (const float*)d_in[18];
    const float* b3    = (const float*)d_in[19];
    const float* W1    = (const float*)d_in[20];
    const float* bw1   = (const float*)d_in[21];
    const float* W2    = (const float*)d_in[22];
    const float* bw2   = (const float*)d_in[23];

    char* ws = (char*)d_ws;
    // ---- ws layout (bytes) ----
    const size_t o_WqkvT = 0;                       // 3072x1024 bf16 = 6291456
    const size_t o_Wo1T  = o_WqkvT + 6291456;       // 1024x1024 bf16
    const size_t o_WkvT  = o_Wo1T  + 2097152;       // 2048x1024 bf16
    const size_t o_WqT   = o_WkvT  + 4194304;
    const size_t o_Wo2T  = o_WqT   + 2097152;
    const size_t o_W1T   = o_Wo2T  + 2097152;       // 4096x1024 bf16
    const size_t o_W2T   = o_W1T   + 8388608;       // 1024x4096 bf16
    const size_t o_xbf   = o_W2T   + 8388608;       // 33554432
    const size_t o_ybf   = o_xbf   + 8388608;
    const size_t o_qkv   = o_ybf   + 8388608;       // 4096x3072 bf16 (later: kv_bf + q2_bf)
    const size_t o_vals  = o_qkv   + 25165824;      // 4096x1024 bf16 (vals / vals2)
    const size_t o_tmp   = o_vals  + 8388608;       // 4096x1024 f32 (attn_tmp/cross_tmp/ffn)
    const size_t o_y1    = o_tmp   + 16777216;      // f32
    const size_t o_y1bf  = o_y1    + 16777216;
    const size_t o_y2    = o_y1bf  + 8388608;       // f32
    const size_t o_y2bf  = o_y2    + 16777216;
    const size_t o_kv    = o_qkv;                   // reuse (qkv dead after attn1)
    const size_t o_q2    = o_qkv + 16777216;
    const size_t o_hbf   = o_xbf;                   // 4096x4096 bf16, reuse [x_bf..kv_bf)

    unsigned short* pWqkvT = (unsigned short*)(ws + o_WqkvT);
    unsigned short* pWo1T  = (unsigned short*)(ws + o_Wo1T);
    unsigned short* pWkvT  = (unsigned short*)(ws + o_WkvT);
    unsigned short* pWqT   = (unsigned short*)(ws + o_WqT);
    unsigned short* pWo2T  = (unsigned short*)(ws + o_Wo2T);
    unsigned short* pW1T   = (unsigned short*)(ws + o_W1T);
    unsigned short* pW2T   = (unsigned short*)(ws + o_W2T);
    unsigned short* pxbf   = (unsigned short*)(ws + o_xbf);
    unsigned short* pybf   = (unsigned short*)(ws + o_ybf);
    unsigned short* pqkv   = (unsigned short*)(ws + o_qkv);
    unsigned short* pvals  = (unsigned short*)(ws + o_vals);
    float*          ptmp   = (float*)(ws + o_tmp);
    float*          py1    = (float*)(ws + o_y1);
    unsigned short* py1bf  = (unsigned short*)(ws + o_y1bf);
    float*          py2    = (float*)(ws + o_y2);
    unsigned short* py2bf  = (unsigned short*)(ws + o_y2bf);
    unsigned short* pkv    = (unsigned short*)(ws + o_kv);
    unsigned short* pq2    = (unsigned short*)(ws + o_q2);
    unsigned short* phbf   = (unsigned short*)(ws + o_hbf);

    const dim3 tb(32, 8);
    // weight transposes (f32 [K,N] -> bf16 [N,K])
    wtrans<<<dim3(3072 / 32, 1024 / 32), tb, 0, stream>>>(Wqkv, pWqkvT, 1024, 3072);
    wtrans<<<dim3(1024 / 32, 1024 / 32), tb, 0, stream>>>(Wo1,  pWo1T,  1024, 1024);
    wtrans<<<dim3(2048 / 32, 1024 / 32), tb, 0, stream>>>(Wkv,  pWkvT,  1024, 2048);
    wtrans<<<dim3(1024 / 32, 1024 / 32), tb, 0, stream>>>(Wq,   pWqT,   1024, 1024);
    wtrans<<<dim3(1024 / 32, 1024 / 32), tb, 0, stream>>>(Wo2,  pWo2T,  1024, 1024);
    wtrans<<<dim3(4096 / 32, 1024 / 32), tb, 0, stream>>>(W1,   pW1T,   1024, 4096);
    wtrans<<<dim3(1024 / 32, 4096 / 32), tb, 0, stream>>>(W2,   pW2T,   4096, 1024);
    // activation casts
    tobf16<<<dim3(MROWS * DMODEL / 2048), dim3(256), 0, stream>>>(x, pxbf, MROWS * DMODEL);
    tobf16<<<dim3(MROWS * DMODEL / 2048), dim3(256), 0, stream>>>(y, pybf, MROWS * DMODEL);

    // ---- self-attention ----
    gemm_bt<0, 0, 1><<<dim3(3072 / 128, MROWS / 128), dim3(256), 0, stream>>>(
        pybf, pWqkvT, bqkv, nullptr, pqkv, MROWS, 3072, 1024);
    attn_fwd<<<dim3(SEQ / 64, BATCH * NHEADS), dim3(256), 0, stream>>>(
        pqkv, 3072, 192, pqkv + 64, 3072, 192, pqkv + 128, 3072, 192,
        mask1, pvals, 1024, 64);
    gemm_bt<0, 1, 0><<<dim3(1024 / 128, MROWS / 128), dim3(256), 0, stream>>>(
        pvals, pWo1T, bo1, ptmp, nullptr, MROWS, 1024, 1024);
    resid_ln<1><<<dim3(MROWS), dim3(256), 0, stream>>>(ptmp, y, g1, b1, py1, py1bf);

    // ---- cross-attention ----
    gemm_bt<0, 0, 1><<<dim3(2048 / 128, MROWS / 128), dim3(256), 0, stream>>>(
        pxbf, pWkvT, bkv, nullptr, pkv, MROWS, 2048, 1024);
    gemm_bt<0, 0, 1><<<dim3(1024 / 128, MROWS / 128), dim3(256), 0, stream>>>(
        py1bf, pWqT, bq, nullptr, pq2, MROWS, 1024, 1024);
    attn_fwd<<<dim3(SEQ / 64, BATCH * NHEADS), dim3(256), 0, stream>>>(
        pq2, 1024, 64, pkv, 2048, 128, pkv + 64, 2048, 128,
        mask2, pvals, 1024, 64);
    gemm_bt<0, 1, 0><<<dim3(1024 / 128, MROWS / 128), dim3(256), 0, stream>>>(
        pvals, pWo2T, bo2, ptmp, nullptr, MROWS, 1024, 1024);
    resid_ln<1><<<dim3(MROWS), dim3(256), 0, stream>>>(ptmp, py1, g2, b2, py2, py2bf);

    // ---- FFN ----
    gemm_bt<1, 0, 1><<<dim3(4096 / 128, MROWS / 128), dim3(256), 0, stream>>>(
        py2bf, pW1T, bw1, nullptr, phbf, MROWS, 4096, 1024);
    gemm_bt<0, 1, 0><<<dim3(1024 / 128, MROWS / 128), dim3(256), 0, stream>>>(
        phbf, pW2T, bw2, ptmp, nullptr, MROWS, 1024, 4096);
    resid_ln<0><<<dim3(MROWS), dim3(256), 0, stream>>>(ptmp, py2, g3, b3, (float*)d_out, nullptr);
}

// Round 3
// 712.522 us; speedup vs baseline: 2.6792x; 2.6792x over previous
//
#include <hip/hip_runtime.h>
#include <hip/hip_bf16.h>

// ---------------- constants ----------------
#define SEQ      2048
#define BATCH    2
#define DMODEL   1024
#define NHEADS   16
#define HDIM     64
#define FFN_DIM  4096
#define MROWS    (BATCH*SEQ)   // 4096

typedef __attribute__((ext_vector_type(8))) short bf16x8;
typedef __attribute__((ext_vector_type(4))) float f32x4;

// ---------------- helpers ----------------
__device__ __forceinline__ unsigned short f2b(float f) {
    union { float f; unsigned int u; } v; v.f = f;
    unsigned int u = v.u;
    return (unsigned short)((u + 0x7FFFu + ((u >> 16) & 1u)) >> 16);  // RNE
}
__device__ __forceinline__ float b2f(unsigned short h) {
    union { unsigned int u; float f; } v; v.u = ((unsigned int)h) << 16;
    return v.f;
}
__device__ __forceinline__ void gload_lds16(const void* g, void* l) {
    __builtin_amdgcn_global_load_lds((const __attribute__((address_space(1))) void*)g,
                                     (__attribute__((address_space(3))) void*)l, 16, 0, 0);
}

// ---------------- W [K][N] f32 -> Wt [N][K] bf16 ----------------
__global__ __launch_bounds__(256) void wtrans(const float* __restrict__ W,
                                              unsigned short* __restrict__ Wt,
                                              int K, int N) {
    __shared__ float t[32][33];
    const int n0 = blockIdx.x * 32, k0 = blockIdx.y * 32;
    const int tx = threadIdx.x, ty = threadIdx.y;   // 32 x 8
#pragma unroll
    for (int i = 0; i < 4; i++)
        t[ty + i * 8][tx] = W[(size_t)(k0 + ty + i * 8) * N + n0 + tx];
    __syncthreads();
#pragma unroll
    for (int i = 0; i < 4; i++) {
        const int n = ty + i * 8;
        Wt[(size_t)(n0 + n) * K + k0 + tx] = f2b(t[tx][n]);
    }
}

// ---------------- f32 -> bf16 flat ----------------
__global__ __launch_bounds__(256) void tobf16(const float* __restrict__ in,
                                              unsigned short* __restrict__ out, int n) {
    const int i = (blockIdx.x * 256 + threadIdx.x) * 8;
    if (i >= n) return;
    float4 a = *(const float4*)(in + i);
    float4 b = *(const float4*)(in + i + 4);
    unsigned short r[8] = {f2b(a.x), f2b(a.y), f2b(a.z), f2b(a.w),
                           f2b(b.x), f2b(b.y), f2b(b.z), f2b(b.w)};
    *(uint4*)(out + i) = *(const uint4*)r;
}

// ---------------- bf16 MFMA GEMM: C[M,N] = A[M,K] @ Bt[N,K]^T + bias ----------------
template <int RELU, int WF32, int WB16>
__global__ __launch_bounds__(256) void gemm_bt(const unsigned short* __restrict__ A,
                                               const unsigned short* __restrict__ Bt,
                                               const float* __restrict__ bias,
                                               float* __restrict__ Cf,
                                               unsigned short* __restrict__ Cb,
                                               int M, int N, int K) {
    __shared__ __align__(16) unsigned short As[128 * 32];
    __shared__ __align__(16) unsigned short Bs[128 * 32];
    const int tid  = threadIdx.x;
    const int lane = tid & 63;
    const int w    = tid >> 6;
    const int m0   = blockIdx.y << 7;
    const int n0   = blockIdx.x << 7;
    const int wr   = (w >> 1) << 6;
    const int wc   = (w & 1) << 6;
    const int srow = lane >> 2;
    const int scol = (lane & 3) << 3;

    f32x4 acc[4][4];
#pragma unroll
    for (int mi = 0; mi < 4; mi++)
#pragma unroll
        for (int ni = 0; ni < 4; ni++) acc[mi][ni] = (f32x4){0.f, 0.f, 0.f, 0.f};

    for (int k0 = 0; k0 < K; k0 += 32) {
#pragma unroll
        for (int t = 0; t < 2; t++) {
            const int rg  = w * 2 + t;
            const int row = (rg << 4) + srow;
            gload_lds16(A  + (size_t)(m0 + row) * K + k0 + scol, (char*)As + (rg << 10));
            gload_lds16(Bt + (size_t)(n0 + row) * K + k0 + scol, (char*)Bs + (rg << 10));
        }
        __syncthreads();
        const int fr = lane & 15;
        const int fk = (lane >> 4) << 3;
        bf16x8 af[4], bfr[4];
#pragma unroll
        for (int i = 0; i < 4; i++) {
            af[i]  = *(const bf16x8*)(As + (wr + (i << 4) + fr) * 32 + fk);
            bfr[i] = *(const bf16x8*)(Bs + (wc + (i << 4) + fr) * 32 + fk);
        }
#pragma unroll
        for (int mi = 0; mi < 4; mi++)
#pragma unroll
            for (int ni = 0; ni < 4; ni++)
                acc[mi][ni] = __builtin_amdgcn_mfma_f32_16x16x32_bf16(af[mi], bfr[ni], acc[mi][ni], 0, 0, 0);
        __syncthreads();
    }

    const int fr = lane & 15;
    const int fq = lane >> 4;
#pragma unroll
    for (int mi = 0; mi < 4; mi++) {
#pragma unroll
        for (int ni = 0; ni < 4; ni++) {
            const int col = n0 + wc + (ni << 4) + fr;
            const float bv = bias[col];
#pragma unroll
            for (int i = 0; i < 4; i++) {
                const int row = m0 + wr + (mi << 4) + (fq << 2) + i;
                float v = acc[mi][ni][i] + bv;
                if (RELU) v = fmaxf(v, 0.f);
                if (WF32) Cf[(size_t)row * N + col] = v;
                if (WB16) Cb[(size_t)row * N + col] = f2b(v);
            }
        }
    }
}

// ---------------- residual + LayerNorm (row = 1024) ----------------
template <int WB16>
__global__ __launch_bounds__(256) void resid_ln(const float* __restrict__ xin,
                                                const float* __restrict__ res,
                                                const float* __restrict__ g,
                                                const float* __restrict__ b,
                                                float* __restrict__ outf,
                                                unsigned short* __restrict__ outb) {
    const int row = blockIdx.x;
    const int tid = threadIdx.x;
    const size_t base = (size_t)row * 1024 + tid * 4;
    float4 xv = *(const float4*)(xin + base);
    float4 rv = *(const float4*)(res + base);
    const float v0 = xv.x + rv.x, v1 = xv.y + rv.y, v2 = xv.z + rv.z, v3 = xv.w + rv.w;
    float s  = v0 + v1 + v2 + v3;
    float sq = v0 * v0 + v1 * v1 + v2 * v2 + v3 * v3;
#pragma unroll
    for (int off = 32; off; off >>= 1) { s += __shfl_xor(s, off); sq += __shfl_xor(sq, off); }
    __shared__ float red[8];
    if ((tid & 63) == 0) { red[tid >> 6] = s; red[4 + (tid >> 6)] = sq; }
    __syncthreads();
    s  = red[0] + red[1] + red[2] + red[3];
    sq = red[4] + red[5] + red[6] + red[7];
    const float mean = s * (1.0f / 1024.0f);
    const float var  = sq * (1.0f / 1024.0f) - mean * mean;
    const float inv  = rsqrtf(var + 1e-5f);
    const int col = tid * 4;
    float4 gv = *(const float4*)(g + col);
    float4 bv = *(const float4*)(b + col);
    const float o0 = (v0 - mean) * inv * gv.x + bv.x;
    const float o1 = (v1 - mean) * inv * gv.y + bv.y;
    const float o2 = (v2 - mean) * inv * gv.z + bv.z;
    const float o3 = (v3 - mean) * inv * gv.w + bv.w;
    float4 ov = {o0, o1, o2, o3};
    *(float4*)(outf + base) = ov;
    if (WB16) {
        uint2 u;
        u.x = (unsigned int)f2b(o0) | ((unsigned int)f2b(o1) << 16);
        u.y = (unsigned int)f2b(o2) | ((unsigned int)f2b(o3) << 16);
        *(uint2*)(outb + base) = u;
    }
}

// ---------------- MFMA flash attention (bf16), QBLK=64 (16 q-rows/wave), KVBLK=64 ----------------
// All LDS tiles: 64 rows x 128B, XOR-swizzled: byte ^= (row&7)<<4.
// Staged via global_load_lds w=16 with pre-swizzled global source chunks (rule #21).
// QK^T swapped: S^T = mfma(K_frag, Q_frag) -> lane stats row q = lane&15.
// V transposed LDS->LDS into Vt[d][kv]; PV: O = mfma(P_frag, Vt_frag).
__global__ __launch_bounds__(256) void attn_mfma(
    const unsigned short* __restrict__ Qb, int q_rs, int q_ho,
    const unsigned short* __restrict__ Kb, int k_rs, int k_ho,
    const unsigned short* __restrict__ Vb, int v_rs, int v_ho,
    const float* __restrict__ mask,
    unsigned short* __restrict__ Ob, int o_rs, int o_ho) {
    __shared__ __align__(16) unsigned short Kls[64 * 64];
    __shared__ __align__(16) unsigned short Vraw[64 * 64];
    __shared__ __align__(16) unsigned short QVt[64 * 64];   // Q (prologue) then Vt
    __shared__ __align__(16) unsigned short Pls[4][16 * 64];

    const int tid  = threadIdx.x;
    const int lane = tid & 63;
    const int w    = tid >> 6;
    const int g    = lane >> 4;       // 0..3
    const int q15  = lane & 15;
    const int swz  = (lane & 7) << 4; // row&7 == lane&7 for all our row formulas
    const int bh   = blockIdx.y;
    const int b    = bh >> 4, h = bh & 15;
    const int q0   = blockIdx.x << 6;
    const size_t rowbase = (size_t)b * SEQ;

    char* Kc = (char*)Kls;
    char* Vc = (char*)Vraw;
    char* Tc = (char*)QVt;
    char* Pc = (char*)(&Pls[w][0]);

    const int hq = h * q_ho, hk = h * k_ho, hv = h * v_ho;

    // stage one 64x64 bf16 tile: chunk c -> lds byte c*16; sources global chunk (c&7)^(r&7)
    auto stage2 = [&](const unsigned short* base, int rs, int hoff, int row0, char* ldsb) {
#pragma unroll
        for (int bb = 0; bb < 2; bb++) {
            const int c = tid + (bb << 8);
            const int r = c >> 3, ci = c & 7;
            gload_lds16(base + (rowbase + row0 + r) * (size_t)rs + hoff + ((ci ^ (r & 7)) << 3),
                        ldsb + ((c >> 6) << 10));
        }
    };

    // prologue: stage Q, K(0), V(0)
    stage2(Qb, q_rs, hq, q0, Tc);
    stage2(Kb, k_rs, hk, 0, Kc);
    stage2(Vb, v_rs, hv, 0, Vc);

    float m_run = -3.0e38f, l_run = 0.f;
    f32x4 oacc[4];
#pragma unroll
    for (int fd = 0; fd < 4; fd++) oacc[fd] = (f32x4){0.f, 0.f, 0.f, 0.f};

    __syncthreads();
    // hoist Q fragments (B-operand: [n=q15][k-slice])
    bf16x8 qf[2];
#pragma unroll
    for (int s = 0; s < 2; s++)
        qf[s] = *(const bf16x8*)(Tc + (w * 16 + q15) * 128 + (((s << 6) + (g << 4)) ^ swz));
    __syncthreads();   // Q_lds now free -> becomes Vt

    const float* mrow_ptr = mask + (size_t)(q0 + w * 16 + q15) * SEQ;

    for (int t = 0; t < 32; t++) {
        const int kv0 = t << 6;
        // ---- V transpose: Vraw[kv][d] -> Vt[d=lane][kv], both swizzled ----
#pragma unroll
        for (int bb = 0; bb < 2; bb++) {
            const int kvb = bb * 32 + w * 8;
            unsigned short t8[8];
#pragma unroll
            for (int m = 0; m < 8; m++)
                t8[m] = *(const unsigned short*)(Vc + (kvb + m) * 128 + ((2 * lane) ^ (m << 4)));
            *(uint4*)(Tc + lane * 128 + ((2 * kvb) ^ swz)) = *(const uint4*)t8;
        }
        // ---- QK^T (swapped): sacc[f] = S^T[kv=f*16+g*4+r][q=q15] ----
        f32x4 sacc[4];
#pragma unroll
        for (int f = 0; f < 4; f++) sacc[f] = (f32x4){0.f, 0.f, 0.f, 0.f};
#pragma unroll
        for (int s = 0; s < 2; s++)
#pragma unroll
            for (int f = 0; f < 4; f++) {
                bf16x8 kf = *(const bf16x8*)(Kc + (f * 16 + q15) * 128 + (((s << 6) + (g << 4)) ^ swz));
                sacc[f] = __builtin_amdgcn_mfma_f32_16x16x32_bf16(kf, qf[s], sacc[f], 0, 0, 0);
            }
        // ---- online softmax (stats row q = q15) ----
        float p[4][4];
        float mt = -3.0e38f;
#pragma unroll
        for (int f = 0; f < 4; f++) {
            float4 mk = *(const float4*)(mrow_ptr + kv0 + f * 16 + g * 4);
            const float* mkp = (const float*)&mk;
#pragma unroll
            for (int r = 0; r < 4; r++) {
                const float v = sacc[f][r] * 0.125f + mkp[r];
                p[f][r] = v;
                mt = fmaxf(mt, v);
            }
        }
        mt = fmaxf(mt, __shfl_xor(mt, 16));
        mt = fmaxf(mt, __shfl_xor(mt, 32));
        const float mnew  = fmaxf(m_run, mt);
        const float alpha = __expf(m_run - mnew);
        m_run = mnew;
        float lsum = 0.f;
#pragma unroll
        for (int f = 0; f < 4; f++)
#pragma unroll
            for (int r = 0; r < 4; r++) {
                const float e = __expf(p[f][r] - mnew);
                p[f][r] = e;
                lsum += e;
            }
        lsum += __shfl_xor(lsum, 16);
        lsum += __shfl_xor(lsum, 32);
        l_run = l_run * alpha + lsum;
        // ---- P -> bf16 into per-wave P_lds (rows q=q15, swizzled) ----
#pragma unroll
        for (int f = 0; f < 4; f++) {
            const unsigned int w0 = (unsigned int)f2b(p[f][0]) | ((unsigned int)f2b(p[f][1]) << 16);
            const unsigned int w1 = (unsigned int)f2b(p[f][2]) | ((unsigned int)f2b(p[f][3]) << 16);
            const int bbase = ((f << 5) + (g << 3)) ^ swz;
            *(unsigned int*)(Pc + q15 * 128 + bbase)     = w0;
            *(unsigned int*)(Pc + q15 * 128 + bbase + 4) = w1;
        }
        __syncthreads();   // Vt complete; K/Vraw consumed
        if (t < 31) {      // prefetch next K/V tiles (overlaps PV)
            stage2(Kb, k_rs, hk, kv0 + 64, Kc);
            stage2(Vb, v_rs, hv, kv0 + 64, Vc);
        }
        // ---- rescale O by alpha (per O-row q' = g*4+r) ----
        float ar[4];
#pragma unroll
        for (int r = 0; r < 4; r++) ar[r] = __shfl(alpha, (g << 4) + (g << 2) + r);
#pragma unroll
        for (int fd = 0; fd < 4; fd++)
#pragma unroll
            for (int r = 0; r < 4; r++) oacc[fd][r] *= ar[r];
        // ---- PV: O += mfma(P_frag, Vt_frag) ----
#pragma unroll
        for (int s = 0; s < 2; s++) {
            const bf16x8 pf = *(const bf16x8*)(Pc + q15 * 128 + (((s << 6) + (g << 4)) ^ swz));
#pragma unroll
            for (int fd = 0; fd < 4; fd++) {
                const bf16x8 vf = *(const bf16x8*)(Tc + (fd * 16 + q15) * 128 + (((s << 6) + (g << 4)) ^ swz));
                oacc[fd] = __builtin_amdgcn_mfma_f32_16x16x32_bf16(pf, vf, oacc[fd], 0, 0, 0);
            }
        }
        __syncthreads();   // PV done (Vt free for next transpose)
    }

    // ---- epilogue: O[q'=g*4+r][d=fd*16+q15] * (1/l) ----
    const float rl = 1.0f / l_run;
    float invr[4];
#pragma unroll
    for (int r = 0; r < 4; r++) invr[r] = __shfl(rl, (g << 4) + (g << 2) + r);
    const size_t orow0 = rowbase + q0 + w * 16;
#pragma unroll
    for (int fd = 0; fd < 4; fd++)
#pragma unroll
        for (int r = 0; r < 4; r++) {
            const int qq = (g << 2) + r;
            Ob[(orow0 + qq) * (size_t)o_rs + h * o_ho + fd * 16 + q15] = f2b(oacc[fd][r] * invr[r]);
        }
}

// ---------------- orchestration ----------------
extern "C" void kernel_launch(void* const* d_in, const int* in_sizes, int n_in,
                              void* d_out, int out_size, void* d_ws, size_t ws_size,
                              hipStream_t stream) {
    const float* x     = (const float*)d_in[0];
    const float* y     = (const float*)d_in[1];
    const float* mask1 = (const float*)d_in[2];
    const float* mask2 = (const float*)d_in[3];
    const float* Wqkv  = (const float*)d_in[4];
    const float* bqkv  = (const float*)d_in[5];
    const float* Wo1   = (const float*)d_in[6];
    const float* bo1   = (const float*)d_in[7];
    const float* Wkv   = (const float*)d_in[8];
    const float* bkv   = (const float*)d_in[9];
    const float* Wq    = (const float*)d_in[10];
    const float* bq    = (const float*)d_in[11];
    const float* Wo2   = (const float*)d_in[12];
    const float* bo2   = (const float*)d_in[13];
    const float* g1    = (const float*)d_in[14];
    const float* b1    = (const float*)d_in[15];
    const float* g2    = (const float*)d_in[16];
    const float* b2    = (const float*)d_in[17];
    const float* g3    = (const float*)d_in[18];
    const float* b3    = (const float*)d_in[19];
    const float* W1    = (const float*)d_in[20];
    const float* bw1   = (const float*)d_in[21];
    const float* W2    = (const float*)d_in[22];
    const float* bw2   = (const float*)d_in[23];

    char* ws = (char*)d_ws;
    const size_t o_WqkvT = 0;
    const size_t o_Wo1T  = o_WqkvT + 6291456;
    const size_t o_WkvT  = o_Wo1T  + 2097152;
    const size_t o_WqT   = o_WkvT  + 4194304;
    const size_t o_Wo2T  = o_WqT   + 2097152;
    const size_t o_W1T   = o_Wo2T  + 2097152;
    const size_t o_W2T   = o_W1T   + 8388608;
    const size_t o_xbf   = o_W2T   + 8388608;
    const size_t o_ybf   = o_xbf   + 8388608;
    const size_t o_qkv   = o_ybf   + 8388608;
    const size_t o_vals  = o_qkv   + 25165824;
    const size_t o_tmp   = o_vals  + 8388608;
    const size_t o_y1    = o_tmp   + 16777216;
    const size_t o_y1bf  = o_y1    + 16777216;
    const size_t o_y2    = o_y1bf  + 8388608;
    const size_t o_y2bf  = o_y2    + 16777216;
    const size_t o_kv    = o_qkv;
    const size_t o_q2    = o_qkv + 16777216;
    const size_t o_hbf   = o_xbf;

    unsigned short* pWqkvT = (unsigned short*)(ws + o_WqkvT);
    unsigned short* pWo1T  = (unsigned short*)(ws + o_Wo1T);
    unsigned short* pWkvT  = (unsigned short*)(ws + o_WkvT);
    unsigned short* pWqT   = (unsigned short*)(ws + o_WqT);
    unsigned short* pWo2T  = (unsigned short*)(ws + o_Wo2T);
    unsigned short* pW1T   = (unsigned short*)(ws + o_W1T);
    unsigned short* pW2T   = (unsigned short*)(ws + o_W2T);
    unsigned short* pxbf   = (unsigned short*)(ws + o_xbf);
    unsigned short* pybf   = (unsigned short*)(ws + o_ybf);
    unsigned short* pqkv   = (unsigned short*)(ws + o_qkv);
    unsigned short* pvals  = (unsigned short*)(ws + o_vals);
    float*          ptmp   = (float*)(ws + o_tmp);
    float*          py1    = (float*)(ws + o_y1);
    unsigned short* py1bf  = (unsigned short*)(ws + o_y1bf);
    float*          py2    = (float*)(ws + o_y2);
    unsigned short* py2bf  = (unsigned short*)(ws + o_y2bf);
    unsigned short* pkv    = (unsigned short*)(ws + o_kv);
    unsigned short* pq2    = (unsigned short*)(ws + o_q2);
    unsigned short* phbf   = (unsigned short*)(ws + o_hbf);

    const dim3 tb(32, 8);
    wtrans<<<dim3(3072 / 32, 1024 / 32), tb, 0, stream>>>(Wqkv, pWqkvT, 1024, 3072);
    wtrans<<<dim3(1024 / 32, 1024 / 32), tb, 0, stream>>>(Wo1,  pWo1T,  1024, 1024);
    wtrans<<<dim3(2048 / 32, 1024 / 32), tb, 0, stream>>>(Wkv,  pWkvT,  1024, 2048);
    wtrans<<<dim3(1024 / 32, 1024 / 32), tb, 0, stream>>>(Wq,   pWqT,   1024, 1024);
    wtrans<<<dim3(1024 / 32, 1024 / 32), tb, 0, stream>>>(Wo2,  pWo2T,  1024, 1024);
    wtrans<<<dim3(4096 / 32, 1024 / 32), tb, 0, stream>>>(W1,   pW1T,   1024, 4096);
    wtrans<<<dim3(1024 / 32, 4096 / 32), tb, 0, stream>>>(W2,   pW2T,   4096, 1024);
    tobf16<<<dim3(MROWS * DMODEL / 2048), dim3(256), 0, stream>>>(x, pxbf, MROWS * DMODEL);
    tobf16<<<dim3(MROWS * DMODEL / 2048), dim3(256), 0, stream>>>(y, pybf, MROWS * DMODEL);

    // ---- self-attention ----
    gemm_bt<0, 0, 1><<<dim3(3072 / 128, MROWS / 128), dim3(256), 0, stream>>>(
        pybf, pWqkvT, bqkv, nullptr, pqkv, MROWS, 3072, 1024);
    attn_mfma<<<dim3(SEQ / 64, BATCH * NHEADS), dim3(256), 0, stream>>>(
        pqkv, 3072, 192, pqkv + 64, 3072, 192, pqkv + 128, 3072, 192,
        mask1, pvals, 1024, 64);
    gemm_bt<0, 1, 0><<<dim3(1024 / 128, MROWS / 128), dim3(256), 0, stream>>>(
        pvals, pWo1T, bo1, ptmp, nullptr, MROWS, 1024, 1024);
    resid_ln<1><<<dim3(MROWS), dim3(256), 0, stream>>>(ptmp, y, g1, b1, py1, py1bf);

    // ---- cross-attention ----
    gemm_bt<0, 0, 1><<<dim3(2048 / 128, MROWS / 128), dim3(256), 0, stream>>>(
        pxbf, pWkvT, bkv, nullptr, pkv, MROWS, 2048, 1024);
    gemm_bt<0, 0, 1><<<dim3(1024 / 128, MROWS / 128), dim3(256), 0, stream>>>(
        py1bf, pWqT, bq, nullptr, pq2, MROWS, 1024, 1024);
    attn_mfma<<<dim3(SEQ / 64, BATCH * NHEADS), dim3(256), 0, stream>>>(
        pq2, 1024, 64, pkv, 2048, 128, pkv + 64, 2048, 128,
        mask2, pvals, 1024, 64);
    gemm_bt<0, 1, 0><<<dim3(1024 / 128, MROWS / 128), dim3(256), 0, stream>>>(
        pvals, pWo2T, bo2, ptmp, nullptr, MROWS, 1024, 1024);
    resid_ln<1><<<dim3(MROWS), dim3(256), 0, stream>>>(ptmp, py1, g2, b2, py2, py2bf);

    // ---- FFN ----
    gemm_bt<1, 0, 1><<<dim3(4096 / 128, MROWS / 128), dim3(256), 0, stream>>>(
        py2bf, pW1T, bw1, nullptr, phbf, MROWS, 4096, 1024);
    gemm_bt<0, 1, 0><<<dim3(1024 / 128, MROWS / 128), dim3(256), 0, stream>>>(
        phbf, pW2T, bw2, ptmp, nullptr, MROWS, 1024, 4096);
    resid_ln<0><<<dim3(MROWS), dim3(256), 0, stream>>>(ptmp, py2, g3, b3, (float*)d_out, nullptr);
}

// Round 5
// 704.176 us; speedup vs baseline: 2.7110x; 1.0119x over previous
//
#include <hip/hip_runtime.h>
#include <hip/hip_bf16.h>

// ---------------- constants ----------------
#define SEQ      2048
#define BATCH    2
#define DMODEL   1024
#define NHEADS   16
#define HDIM     64
#define FFN_DIM  4096
#define MROWS    (BATCH*SEQ)   // 4096

typedef __attribute__((ext_vector_type(8))) short bf16x8;
typedef __attribute__((ext_vector_type(4))) float f32x4;

#define GFENCE() asm volatile("" ::: "memory")
#define SBAR()   do { GFENCE(); __builtin_amdgcn_s_barrier(); GFENCE(); } while (0)

// ---------------- helpers ----------------
__device__ __forceinline__ unsigned short f2b(float f) {
    union { float f; unsigned int u; } v; v.f = f;
    unsigned int u = v.u;
    return (unsigned short)((u + 0x7FFFu + ((u >> 16) & 1u)) >> 16);  // RNE
}
__device__ __forceinline__ float b2f(unsigned short h) {
    union { unsigned int u; float f; } v; v.u = ((unsigned int)h) << 16;
    return v.f;
}
__device__ __forceinline__ void gload_lds16(const void* g, void* l) {
    __builtin_amdgcn_global_load_lds((const __attribute__((address_space(1))) void*)g,
                                     (__attribute__((address_space(3))) void*)l, 16, 0, 0);
}

// ---------------- W [K][N] f32 -> Wt [N][K] bf16 ----------------
__global__ __launch_bounds__(256) void wtrans(const float* __restrict__ W,
                                              unsigned short* __restrict__ Wt,
                                              int K, int N) {
    __shared__ float t[32][33];
    const int n0 = blockIdx.x * 32, k0 = blockIdx.y * 32;
    const int tx = threadIdx.x, ty = threadIdx.y;   // 32 x 8
#pragma unroll
    for (int i = 0; i < 4; i++)
        t[ty + i * 8][tx] = W[(size_t)(k0 + ty + i * 8) * N + n0 + tx];
    __syncthreads();
#pragma unroll
    for (int i = 0; i < 4; i++) {
        const int n = ty + i * 8;
        Wt[(size_t)(n0 + n) * K + k0 + tx] = f2b(t[tx][n]);
    }
}

// ---------------- f32 -> bf16 flat ----------------
__global__ __launch_bounds__(256) void tobf16(const float* __restrict__ in,
                                              unsigned short* __restrict__ out, int n) {
    const int i = (blockIdx.x * 256 + threadIdx.x) * 8;
    if (i >= n) return;
    float4 a = *(const float4*)(in + i);
    float4 b = *(const float4*)(in + i + 4);
    unsigned short r[8] = {f2b(a.x), f2b(a.y), f2b(a.z), f2b(a.w),
                           f2b(b.x), f2b(b.y), f2b(b.z), f2b(b.w)};
    *(uint4*)(out + i) = *(const uint4*)r;
}

// ---------------- bf16 MFMA GEMM (128x128, 2-barrier): C = A @ Bt^T + bias ----------------
template <int RELU, int WF32, int WB16>
__global__ __launch_bounds__(256) void gemm_bt(const unsigned short* __restrict__ A,
                                               const unsigned short* __restrict__ Bt,
                                               const float* __restrict__ bias,
                                               float* __restrict__ Cf,
                                               unsigned short* __restrict__ Cb,
                                               int M, int N, int K) {
    __shared__ __align__(16) unsigned short As[128 * 32];
    __shared__ __align__(16) unsigned short Bs[128 * 32];
    const int tid  = threadIdx.x;
    const int lane = tid & 63;
    const int w    = tid >> 6;
    const int m0   = blockIdx.y << 7;
    const int n0   = blockIdx.x << 7;
    const int wr   = (w >> 1) << 6;
    const int wc   = (w & 1) << 6;
    const int srow = lane >> 2;
    const int scol = (lane & 3) << 3;

    f32x4 acc[4][4];
#pragma unroll
    for (int mi = 0; mi < 4; mi++)
#pragma unroll
        for (int ni = 0; ni < 4; ni++) acc[mi][ni] = (f32x4){0.f, 0.f, 0.f, 0.f};

    for (int k0 = 0; k0 < K; k0 += 32) {
#pragma unroll
        for (int t = 0; t < 2; t++) {
            const int rg  = w * 2 + t;
            const int row = (rg << 4) + srow;
            gload_lds16(A  + (size_t)(m0 + row) * K + k0 + scol, (char*)As + (rg << 10));
            gload_lds16(Bt + (size_t)(n0 + row) * K + k0 + scol, (char*)Bs + (rg << 10));
        }
        __syncthreads();
        const int fr = lane & 15;
        const int fk = (lane >> 4) << 3;
        bf16x8 af[4], bfr[4];
#pragma unroll
        for (int i = 0; i < 4; i++) {
            af[i]  = *(const bf16x8*)(As + (wr + (i << 4) + fr) * 32 + fk);
            bfr[i] = *(const bf16x8*)(Bs + (wc + (i << 4) + fr) * 32 + fk);
        }
#pragma unroll
        for (int mi = 0; mi < 4; mi++)
#pragma unroll
            for (int ni = 0; ni < 4; ni++)
                acc[mi][ni] = __builtin_amdgcn_mfma_f32_16x16x32_bf16(af[mi], bfr[ni], acc[mi][ni], 0, 0, 0);
        __syncthreads();
    }

    const int fr = lane & 15;
    const int fq = lane >> 4;
#pragma unroll
    for (int mi = 0; mi < 4; mi++) {
#pragma unroll
        for (int ni = 0; ni < 4; ni++) {
            const int col = n0 + wc + (ni << 4) + fr;
            const float bv = bias[col];
#pragma unroll
            for (int i = 0; i < 4; i++) {
                const int row = m0 + wr + (mi << 4) + (fq << 2) + i;
                float v = acc[mi][ni][i] + bv;
                if (RELU) v = fmaxf(v, 0.f);
                if (WF32) Cf[(size_t)row * N + col] = v;
                if (WB16) Cb[(size_t)row * N + col] = f2b(v);
            }
        }
    }
}

// ---------------- bf16 MFMA GEMM (256x256, 8-wave, 4-phase counted-vmcnt dbuf) ----------------
// BM=BN=256, BK=64. LDS 128KB: [2 buf][A|B][256 rows x 64 k] bf16, XOR-swizzled
// via pre-swizzled global source (rule #21): LDS[row][ci] holds global k-chunk ci^(row&7).
// Per K-tile: 4 phases {stage 1 half-tile, counted vmcnt, barrier, ds_read frags,
// setprio(1), 16 MFMA, setprio(0), barrier}. Stage order per tile: B-h0,B-h1,A-h0,A-h1,
// where h selects the mh rows of BOTH wave groups: trow = ((r>>6)<<7) + h*64 + (r&63).
// Waits: vmcnt(4) at p0/p1 (steady); final tile vmcnt(2)/vmcnt(0). Never 0 mid-loop.
template <int RELU, int WF32, int WB16>
__global__ __launch_bounds__(512, 2) void gemm256(const unsigned short* __restrict__ A,
                                                  const unsigned short* __restrict__ Bt,
                                                  const float* __restrict__ bias,
                                                  float* __restrict__ Cf,
                                                  unsigned short* __restrict__ Cb,
                                                  int M, int N, int K) {
    __shared__ __align__(16) unsigned short lds[2][2][256 * 64];   // [buf][0=A,1=B]
    const int tid  = threadIdx.x;
    const int lane = tid & 63;
    const int w    = tid >> 6;        // 0..7
    const int q15  = lane & 15;
    const int g    = lane >> 4;       // 0..3
    const int m0   = blockIdx.y << 8;
    const int n0   = blockIdx.x << 8;
    const int wr   = (w >> 2) << 7;   // 0 / 128
    const int wc   = (w & 3) << 6;    // 0 / 64 / 128 / 192

    f32x4 acc[8][4];
#pragma unroll
    for (int m = 0; m < 8; m++)
#pragma unroll
        for (int n = 0; n < 4; n++) acc[m][n] = (f32x4){0.f, 0.f, 0.f, 0.f};

    const int NT = K >> 6;

    // stage one 16KB half-tile (2 gload_lds per thread, lds dest linear per window)
    auto stage = [&](int which, int buf, int h, int kt, const unsigned short* src, int base0) {
        char* ldsb = (char*)&lds[buf][which][0];
#pragma unroll
        for (int j = 0; j < 2; j++) {
            const int c    = (w << 7) + (j << 6) + lane;
            const int r    = c >> 3, ci = c & 7;
            const int trow = ((r >> 6) << 7) + (h << 6) + (r & 63);
            const int r0   = (w << 4) + (j << 3);
            const int tr0  = ((r0 >> 6) << 7) + (h << 6) + (r0 & 63);
            gload_lds16(src + (size_t)(base0 + trow) * K + (kt << 6) + ((ci ^ (r & 7)) << 3),
                        ldsb + tr0 * 128);
        }
    };
    auto ldA = [&](int buf, int row, int kc) -> bf16x8 {
        return *(const bf16x8*)((const char*)&lds[buf][0][0] + row * 128 + ((kc ^ (row & 7)) << 4));
    };
    auto ldB = [&](int buf, int row, int kc) -> bf16x8 {
        return *(const bf16x8*)((const char*)&lds[buf][1][0] + row * 128 + ((kc ^ (row & 7)) << 4));
    };

    // prologue: tile 0 -> buf 0, order B0,B1,A0,A1 (8 loads/wave outstanding)
    stage(1, 0, 0, 0, Bt, n0);
    stage(1, 0, 1, 0, Bt, n0);
    stage(0, 0, 0, 0, A, m0);
    stage(0, 0, 1, 0, A, m0);

    for (int t = 0; t < NT; ++t) {
        const int buf = t & 1, nb = buf ^ 1;
        const bool st = (t + 1 < NT);
        bf16x8 bfr[4], af[4];

        // ---------- phase 0: mh=0, ks=0 (needs B-all + A-h0) ----------
        if (st) { stage(1, nb, 0, t + 1, Bt, n0);
                  asm volatile("s_waitcnt vmcnt(4)" ::: "memory"); }
        else    { asm volatile("s_waitcnt vmcnt(2)" ::: "memory"); }
        SBAR();
#pragma unroll
        for (int n = 0; n < 4; n++) bfr[n] = ldB(buf, wc + n * 16 + q15, g);
#pragma unroll
        for (int m = 0; m < 4; m++) af[m]  = ldA(buf, wr + m * 16 + q15, g);
        __builtin_amdgcn_s_setprio(1);
#pragma unroll
        for (int m = 0; m < 4; m++)
#pragma unroll
            for (int n = 0; n < 4; n++)
                acc[m][n] = __builtin_amdgcn_mfma_f32_16x16x32_bf16(af[m], bfr[n], acc[m][n], 0, 0, 0);
        __builtin_amdgcn_s_setprio(0);
        SBAR();

        // ---------- phase 1: mh=1, ks=0 (needs A-h1; reuse bfr) ----------
        if (st) { stage(1, nb, 1, t + 1, Bt, n0);
                  asm volatile("s_waitcnt vmcnt(4)" ::: "memory"); }
        else    { asm volatile("s_waitcnt vmcnt(0)" ::: "memory"); }
        SBAR();
#pragma unroll
        for (int m = 0; m < 4; m++) af[m] = ldA(buf, wr + 64 + m * 16 + q15, g);
        __builtin_amdgcn_s_setprio(1);
#pragma unroll
        for (int m = 0; m < 4; m++)
#pragma unroll
            for (int n = 0; n < 4; n++)
                acc[4 + m][n] = __builtin_amdgcn_mfma_f32_16x16x32_bf16(af[m], bfr[n], acc[4 + m][n], 0, 0, 0);
        __builtin_amdgcn_s_setprio(0);
        SBAR();

        // ---------- phase 2: mh=0, ks=1 (data already resident) ----------
        if (st) stage(0, nb, 0, t + 1, A, m0);
        SBAR();
#pragma unroll
        for (int n = 0; n < 4; n++) bfr[n] = ldB(buf, wc + n * 16 + q15, 4 + g);
#pragma unroll
        for (int m = 0; m < 4; m++) af[m]  = ldA(buf, wr + m * 16 + q15, 4 + g);
        __builtin_amdgcn_s_setprio(1);
#pragma unroll
        for (int m = 0; m < 4; m++)
#pragma unroll
            for (int n = 0; n < 4; n++)
                acc[m][n] = __builtin_amdgcn_mfma_f32_16x16x32_bf16(af[m], bfr[n], acc[m][n], 0, 0, 0);
        __builtin_amdgcn_s_setprio(0);
        SBAR();

        // ---------- phase 3: mh=1, ks=1 ----------
        if (st) stage(0, nb, 1, t + 1, A, m0);
        SBAR();
#pragma unroll
        for (int m = 0; m < 4; m++) af[m] = ldA(buf, wr + 64 + m * 16 + q15, 4 + g);
        __builtin_amdgcn_s_setprio(1);
#pragma unroll
        for (int m = 0; m < 4; m++)
#pragma unroll
            for (int n = 0; n < 4; n++)
                acc[4 + m][n] = __builtin_amdgcn_mfma_f32_16x16x32_bf16(af[m], bfr[n], acc[4 + m][n], 0, 0, 0);
        __builtin_amdgcn_s_setprio(0);
        SBAR();
    }

    // ---------- epilogue ----------
#pragma unroll
    for (int mh = 0; mh < 2; mh++)
#pragma unroll
        for (int mf = 0; mf < 4; mf++)
#pragma unroll
            for (int nf = 0; nf < 4; nf++) {
                const int col = n0 + wc + nf * 16 + q15;
                const float bv = bias[col];
#pragma unroll
                for (int i = 0; i < 4; i++) {
                    const int row = m0 + wr + mh * 64 + mf * 16 + (g << 2) + i;
                    float v = acc[mh * 4 + mf][nf][i] + bv;
                    if (RELU) v = fmaxf(v, 0.f);
                    if (WF32) Cf[(size_t)row * N + col] = v;
                    if (WB16) Cb[(size_t)row * N + col] = f2b(v);
                }
            }
}

// ---------------- residual + LayerNorm (row = 1024) ----------------
template <int WB16>
__global__ __launch_bounds__(256) void resid_ln(const float* __restrict__ xin,
                                                const float* __restrict__ res,
                                                const float* __restrict__ g,
                                                const float* __restrict__ b,
                                                float* __restrict__ outf,
                                                unsigned short* __restrict__ outb) {
    const int row = blockIdx.x;
    const int tid = threadIdx.x;
    const size_t base = (size_t)row * 1024 + tid * 4;
    float4 xv = *(const float4*)(xin + base);
    float4 rv = *(const float4*)(res + base);
    const float v0 = xv.x + rv.x, v1 = xv.y + rv.y, v2 = xv.z + rv.z, v3 = xv.w + rv.w;
    float s  = v0 + v1 + v2 + v3;
    float sq = v0 * v0 + v1 * v1 + v2 * v2 + v3 * v3;
#pragma unroll
    for (int off = 32; off; off >>= 1) { s += __shfl_xor(s, off); sq += __shfl_xor(sq, off); }
    __shared__ float red[8];
    if ((tid & 63) == 0) { red[tid >> 6] = s; red[4 + (tid >> 6)] = sq; }
    __syncthreads();
    s  = red[0] + red[1] + red[2] + red[3];
    sq = red[4] + red[5] + red[6] + red[7];
    const float mean = s * (1.0f / 1024.0f);
    const float var  = sq * (1.0f / 1024.0f) - mean * mean;
    const float inv  = rsqrtf(var + 1e-5f);
    const int col = tid * 4;
    float4 gv = *(const float4*)(g + col);
    float4 bv = *(const float4*)(b + col);
    const float o0 = (v0 - mean) * inv * gv.x + bv.x;
    const float o1 = (v1 - mean) * inv * gv.y + bv.y;
    const float o2 = (v2 - mean) * inv * gv.z + bv.z;
    const float o3 = (v3 - mean) * inv * gv.w + bv.w;
    float4 ov = {o0, o1, o2, o3};
    *(float4*)(outf + base) = ov;
    if (WB16) {
        uint2 u;
        u.x = (unsigned int)f2b(o0) | ((unsigned int)f2b(o1) << 16);
        u.y = (unsigned int)f2b(o2) | ((unsigned int)f2b(o3) << 16);
        *(uint2*)(outb + base) = u;
    }
}

// ---------------- MFMA flash attention (bf16), QBLK=64, KVBLK=64 ----------------
__global__ __launch_bounds__(256) void attn_mfma(
    const unsigned short* __restrict__ Qb, int q_rs, int q_ho,
    const unsigned short* __restrict__ Kb, int k_rs, int k_ho,
    const unsigned short* __restrict__ Vb, int v_rs, int v_ho,
    const float* __restrict__ mask,
    unsigned short* __restrict__ Ob, int o_rs, int o_ho) {
    __shared__ __align__(16) unsigned short Kls[64 * 64];
    __shared__ __align__(16) unsigned short Vraw[64 * 64];
    __shared__ __align__(16) unsigned short QVt[64 * 64];   // Q (prologue) then Vt
    __shared__ __align__(16) unsigned short Pls[4][16 * 64];

    const int tid  = threadIdx.x;
    const int lane = tid & 63;
    const int w    = tid >> 6;
    const int g    = lane >> 4;
    const int q15  = lane & 15;
    const int swz  = (lane & 7) << 4;
    const int bh   = blockIdx.y;
    const int b    = bh >> 4, h = bh & 15;
    const int q0   = blockIdx.x << 6;
    const size_t rowbase = (size_t)b * SEQ;

    char* Kc = (char*)Kls;
    char* Vc = (char*)Vraw;
    char* Tc = (char*)QVt;
    char* Pc = (char*)(&Pls[w][0]);

    const int hq = h * q_ho, hk = h * k_ho, hv = h * v_ho;

    auto stage2 = [&](const unsigned short* base, int rs, int hoff, int row0, char* ldsb) {
#pragma unroll
        for (int bb = 0; bb < 2; bb++) {
            const int c = tid + (bb << 8);
            const int r = c >> 3, ci = c & 7;
            gload_lds16(base + (rowbase + row0 + r) * (size_t)rs + hoff + ((ci ^ (r & 7)) << 3),
                        ldsb + ((c >> 6) << 10));
        }
    };

    stage2(Qb, q_rs, hq, q0, Tc);
    stage2(Kb, k_rs, hk, 0, Kc);
    stage2(Vb, v_rs, hv, 0, Vc);

    float m_run = -3.0e38f, l_run = 0.f;
    f32x4 oacc[4];
#pragma unroll
    for (int fd = 0; fd < 4; fd++) oacc[fd] = (f32x4){0.f, 0.f, 0.f, 0.f};

    __syncthreads();
    bf16x8 qf[2];
#pragma unroll
    for (int s = 0; s < 2; s++)
        qf[s] = *(const bf16x8*)(Tc + (w * 16 + q15) * 128 + (((s << 6) + (g << 4)) ^ swz));
    __syncthreads();

    const float* mrow_ptr = mask + (size_t)(q0 + w * 16 + q15) * SEQ;

    for (int t = 0; t < 32; t++) {
        const int kv0 = t << 6;
#pragma unroll
        for (int bb = 0; bb < 2; bb++) {
            const int kvb = bb * 32 + w * 8;
            unsigned short t8[8];
#pragma unroll
            for (int m = 0; m < 8; m++)
                t8[m] = *(const unsigned short*)(Vc + (kvb + m) * 128 + ((2 * lane) ^ (m << 4)));
            *(uint4*)(Tc + lane * 128 + ((2 * kvb) ^ swz)) = *(const uint4*)t8;
        }
        f32x4 sacc[4];
#pragma unroll
        for (int f = 0; f < 4; f++) sacc[f] = (f32x4){0.f, 0.f, 0.f, 0.f};
#pragma unroll
        for (int s = 0; s < 2; s++)
#pragma unroll
            for (int f = 0; f < 4; f++) {
                bf16x8 kf = *(const bf16x8*)(Kc + (f * 16 + q15) * 128 + (((s << 6) + (g << 4)) ^ swz));
                sacc[f] = __builtin_amdgcn_mfma_f32_16x16x32_bf16(kf, qf[s], sacc[f], 0, 0, 0);
            }
        float p[4][4];
        float mt = -3.0e38f;
#pragma unroll
        for (int f = 0; f < 4; f++) {
            float4 mk = *(const float4*)(mrow_ptr + kv0 + f * 16 + g * 4);
            const float* mkp = (const float*)&mk;
#pragma unroll
            for (int r = 0; r < 4; r++) {
                const float v = sacc[f][r] * 0.125f + mkp[r];
                p[f][r] = v;
                mt = fmaxf(mt, v);
            }
        }
        mt = fmaxf(mt, __shfl_xor(mt, 16));
        mt = fmaxf(mt, __shfl_xor(mt, 32));
        const float mnew  = fmaxf(m_run, mt);
        const float alpha = __expf(m_run - mnew);
        m_run = mnew;
        float lsum = 0.f;
#pragma unroll
        for (int f = 0; f < 4; f++)
#pragma unroll
            for (int r = 0; r < 4; r++) {
                const float e = __expf(p[f][r] - mnew);
                p[f][r] = e;
                lsum += e;
            }
        lsum += __shfl_xor(lsum, 16);
        lsum += __shfl_xor(lsum, 32);
        l_run = l_run * alpha + lsum;
#pragma unroll
        for (int f = 0; f < 4; f++) {
            const unsigned int w0 = (unsigned int)f2b(p[f][0]) | ((unsigned int)f2b(p[f][1]) << 16);
            const unsigned int w1 = (unsigned int)f2b(p[f][2]) | ((unsigned int)f2b(p[f][3]) << 16);
            const int bbase = ((f << 5) + (g << 3)) ^ swz;
            *(unsigned int*)(Pc + q15 * 128 + bbase)     = w0;
            *(unsigned int*)(Pc + q15 * 128 + bbase + 4) = w1;
        }
        __syncthreads();
        if (t < 31) {
            stage2(Kb, k_rs, hk, kv0 + 64, Kc);
            stage2(Vb, v_rs, hv, kv0 + 64, Vc);
        }
        float ar[4];
#pragma unroll
        for (int r = 0; r < 4; r++) ar[r] = __shfl(alpha, (g << 4) + (g << 2) + r);
#pragma unroll
        for (int fd = 0; fd < 4; fd++)
#pragma unroll
            for (int r = 0; r < 4; r++) oacc[fd][r] *= ar[r];
#pragma unroll
        for (int s = 0; s < 2; s++) {
            const bf16x8 pf = *(const bf16x8*)(Pc + q15 * 128 + (((s << 6) + (g << 4)) ^ swz));
#pragma unroll
            for (int fd = 0; fd < 4; fd++) {
                const bf16x8 vf = *(const bf16x8*)(Tc + (fd * 16 + q15) * 128 + (((s << 6) + (g << 4)) ^ swz));
                oacc[fd] = __builtin_amdgcn_mfma_f32_16x16x32_bf16(pf, vf, oacc[fd], 0, 0, 0);
            }
        }
        __syncthreads();
    }

    const float rl = 1.0f / l_run;
    float invr[4];
#pragma unroll
    for (int r = 0; r < 4; r++) invr[r] = __shfl(rl, (g << 4) + (g << 2) + r);
    const size_t orow0 = rowbase + q0 + w * 16;
#pragma unroll
    for (int fd = 0; fd < 4; fd++)
#pragma unroll
        for (int r = 0; r < 4; r++) {
            const int qq = (g << 2) + r;
            Ob[(orow0 + qq) * (size_t)o_rs + h * o_ho + fd * 16 + q15] = f2b(oacc[fd][r] * invr[r]);
        }
}

// ---------------- orchestration ----------------
extern "C" void kernel_launch(void* const* d_in, const int* in_sizes, int n_in,
                              void* d_out, int out_size, void* d_ws, size_t ws_size,
                              hipStream_t stream) {
    const float* x     = (const float*)d_in[0];
    const float* y     = (const float*)d_in[1];
    const float* mask1 = (const float*)d_in[2];
    const float* mask2 = (const float*)d_in[3];
    const float* Wqkv  = (const float*)d_in[4];
    const float* bqkv  = (const float*)d_in[5];
    const float* Wo1   = (const float*)d_in[6];
    const float* bo1   = (const float*)d_in[7];
    const float* Wkv   = (const float*)d_in[8];
    const float* bkv   = (const float*)d_in[9];
    const float* Wq    = (const float*)d_in[10];
    const float* bq    = (const float*)d_in[11];
    const float* Wo2   = (const float*)d_in[12];
    const float* bo2   = (const float*)d_in[13];
    const float* g1    = (const float*)d_in[14];
    const float* b1    = (const float*)d_in[15];
    const float* g2    = (const float*)d_in[16];
    const float* b2    = (const float*)d_in[17];
    const float* g3    = (const float*)d_in[18];
    const float* b3    = (const float*)d_in[19];
    const float* W1    = (const float*)d_in[20];
    const float* bw1   = (const float*)d_in[21];
    const float* W2    = (const float*)d_in[22];
    const float* bw2   = (const float*)d_in[23];

    char* ws = (char*)d_ws;
    const size_t o_WqkvT = 0;
    const size_t o_Wo1T  = o_WqkvT + 6291456;
    const size_t o_WkvT  = o_Wo1T  + 2097152;
    const size_t o_WqT   = o_WkvT  + 4194304;
    const size_t o_Wo2T  = o_WqT   + 2097152;
    const size_t o_W1T   = o_Wo2T  + 2097152;
    const size_t o_W2T   = o_W1T   + 8388608;
    const size_t o_xbf   = o_W2T   + 8388608;
    const size_t o_ybf   = o_xbf   + 8388608;
    const size_t o_qkv   = o_ybf   + 8388608;
    const size_t o_vals  = o_qkv   + 25165824;
    const size_t o_tmp   = o_vals  + 8388608;
    const size_t o_y1    = o_tmp   + 16777216;
    const size_t o_y1bf  = o_y1    + 16777216;
    const size_t o_y2    = o_y1bf  + 8388608;
    const size_t o_y2bf  = o_y2    + 16777216;
    const size_t o_kv    = o_qkv;
    const size_t o_q2    = o_qkv + 16777216;
    const size_t o_hbf   = o_xbf;

    unsigned short* pWqkvT = (unsigned short*)(ws + o_WqkvT);
    unsigned short* pWo1T  = (unsigned short*)(ws + o_Wo1T);
    unsigned short* pWkvT  = (unsigned short*)(ws + o_WkvT);
    unsigned short* pWqT   = (unsigned short*)(ws + o_WqT);
    unsigned short* pWo2T  = (unsigned short*)(ws + o_Wo2T);
    unsigned short* pW1T   = (unsigned short*)(ws + o_W1T);
    unsigned short* pW2T   = (unsigned short*)(ws + o_W2T);
    unsigned short* pxbf   = (unsigned short*)(ws + o_xbf);
    unsigned short* pybf   = (unsigned short*)(ws + o_ybf);
    unsigned short* pqkv   = (unsigned short*)(ws + o_qkv);
    unsigned short* pvals  = (unsigned short*)(ws + o_vals);
    float*          ptmp   = (float*)(ws + o_tmp);
    float*          py1    = (float*)(ws + o_y1);
    unsigned short* py1bf  = (unsigned short*)(ws + o_y1bf);
    float*          py2    = (float*)(ws + o_y2);
    unsigned short* py2bf  = (unsigned short*)(ws + o_y2bf);
    unsigned short* pkv    = (unsigned short*)(ws + o_kv);
    unsigned short* pq2    = (unsigned short*)(ws + o_q2);
    unsigned short* phbf   = (unsigned short*)(ws + o_hbf);

    const dim3 tb(32, 8);
    wtrans<<<dim3(3072 / 32, 1024 / 32), tb, 0, stream>>>(Wqkv, pWqkvT, 1024, 3072);
    wtrans<<<dim3(1024 / 32, 1024 / 32), tb, 0, stream>>>(Wo1,  pWo1T,  1024, 1024);
    wtrans<<<dim3(2048 / 32, 1024 / 32), tb, 0, stream>>>(Wkv,  pWkvT,  1024, 2048);
    wtrans<<<dim3(1024 / 32, 1024 / 32), tb, 0, stream>>>(Wq,   pWqT,   1024, 1024);
    wtrans<<<dim3(1024 / 32, 1024 / 32), tb, 0, stream>>>(Wo2,  pWo2T,  1024, 1024);
    wtrans<<<dim3(4096 / 32, 1024 / 32), tb, 0, stream>>>(W1,   pW1T,   1024, 4096);
    wtrans<<<dim3(1024 / 32, 4096 / 32), tb, 0, stream>>>(W2,   pW2T,   4096, 1024);
    tobf16<<<dim3(MROWS * DMODEL / 2048), dim3(256), 0, stream>>>(x, pxbf, MROWS * DMODEL);
    tobf16<<<dim3(MROWS * DMODEL / 2048), dim3(256), 0, stream>>>(y, pybf, MROWS * DMODEL);

    // ---- self-attention ----
    gemm256<0, 0, 1><<<dim3(3072 / 256, MROWS / 256), dim3(512), 0, stream>>>(
        pybf, pWqkvT, bqkv, nullptr, pqkv, MROWS, 3072, 1024);
    attn_mfma<<<dim3(SEQ / 64, BATCH * NHEADS), dim3(256), 0, stream>>>(
        pqkv, 3072, 192, pqkv + 64, 3072, 192, pqkv + 128, 3072, 192,
        mask1, pvals, 1024, 64);
    gemm_bt<0, 1, 0><<<dim3(1024 / 128, MROWS / 128), dim3(256), 0, stream>>>(
        pvals, pWo1T, bo1, ptmp, nullptr, MROWS, 1024, 1024);
    resid_ln<1><<<dim3(MROWS), dim3(256), 0, stream>>>(ptmp, y, g1, b1, py1, py1bf);

    // ---- cross-attention ----
    gemm256<0, 0, 1><<<dim3(2048 / 256, MROWS / 256), dim3(512), 0, stream>>>(
        pxbf, pWkvT, bkv, nullptr, pkv, MROWS, 2048, 1024);
    gemm_bt<0, 0, 1><<<dim3(1024 / 128, MROWS / 128), dim3(256), 0, stream>>>(
        py1bf, pWqT, bq, nullptr, pq2, MROWS, 1024, 1024);
    attn_mfma<<<dim3(SEQ / 64, BATCH * NHEADS), dim3(256), 0, stream>>>(
        pq2, 1024, 64, pkv, 2048, 128, pkv + 64, 2048, 128,
        mask2, pvals, 1024, 64);
    gemm_bt<0, 1, 0><<<dim3(1024 / 128, MROWS / 128), dim3(256), 0, stream>>>(
        pvals, pWo2T, bo2, ptmp, nullptr, MROWS, 1024, 1024);
    resid_ln<1><<<dim3(MROWS), dim3(256), 0, stream>>>(ptmp, py1, g2, b2, py2, py2bf);

    // ---- FFN ----
    gemm256<1, 0, 1><<<dim3(4096 / 256, MROWS / 256), dim3(512), 0, stream>>>(
        py2bf, pW1T, bw1, nullptr, phbf, MROWS, 4096, 1024);
    gemm_bt<0, 1, 0><<<dim3(1024 / 128, MROWS / 128), dim3(256), 0, stream>>>(
        phbf, pW2T, bw2, ptmp, nullptr, MROWS, 1024, 4096);
    resid_ln<0><<<dim3(MROWS), dim3(256), 0, stream>>>(ptmp, py2, g3, b3, (float*)d_out, nullptr);
}